// Round 1
// baseline (536.533 us; speedup 1.0000x reference)
//
#include <hip/hip_runtime.h>

// Problem constants (from setup_inputs): B=32, N=8, Lq=256, Ld=512, D=768
#define BB 32
#define NN 8
#define LQ 256
#define LD 512
#define DD 768

#define QSUM_ELEMS (BB * DD)   // 24576 floats in ws
#define NSLOTS 64              // spread-atomic partial slots
#define LQ_CHUNKS 8            // grid.y split of Lq in qsum kernel
#define CH 8                   // l-chunks per (b,n) doc in docs kernel
#define LCHUNK (LD / CH)       // 64 rows per block

// ---------------------------------------------------------------------------
// Kernel 1: qsum[b,d] = sum_lq questions[b,lq,d]   (atomic over Lq chunks)
// ---------------------------------------------------------------------------
__global__ void qsum_kernel(const float* __restrict__ q, float* __restrict__ qsum) {
    int t = blockIdx.x * blockDim.x + threadIdx.x;   // 0 .. B*D-1 (24576)
    int b = t / DD;
    int d = t - b * DD;
    int lq0 = blockIdx.y * (LQ / LQ_CHUNKS);         // 32 lq per chunk
    const float* p = q + ((size_t)b * LQ + lq0) * DD + d;
    float acc = 0.f;
#pragma unroll 8
    for (int i = 0; i < LQ / LQ_CHUNKS; ++i) {
        acc += p[(size_t)i * DD];                    // lanes: consecutive d -> coalesced
    }
    atomicAdd(&qsum[t], acc);
}

// ---------------------------------------------------------------------------
// Kernel 2: stream docs once. Block = (b,n, l-chunk), 192 threads = 3 waves.
// Thread t owns float4 column d = 4t; its qsum fragment is loop-invariant.
// ---------------------------------------------------------------------------
__global__ void __launch_bounds__(192)
docs_kernel(const float* __restrict__ docs, const int* __restrict__ is_ans,
            const float* __restrict__ qsum, float* __restrict__ slots) {
    int bn    = blockIdx.x / CH;          // 0 .. 255
    int chunk = blockIdx.x - bn * CH;     // 0 .. 7
    int b     = bn >> 3;                  // bn / N
    int t     = threadIdx.x;              // 0 .. 191

    const float4 qv = *(const float4*)(qsum + (size_t)b * DD + 4 * t);

    const float4* p = (const float4*)(docs + ((size_t)bn * LD + (size_t)chunk * LCHUNK) * DD) + t;

    float4 acc = make_float4(0.f, 0.f, 0.f, 0.f);
#pragma unroll 4
    for (int l = 0; l < LCHUNK; ++l) {
        float4 v = p[(size_t)l * (DD / 4)];   // 16B/lane, 192 lanes cover one row
        acc.x += v.x * qv.x;
        acc.y += v.y * qv.y;
        acc.z += v.z * qv.z;
        acc.w += v.w * qv.w;
    }
    float s = acc.x + acc.y + acc.z + acc.w;

    // wave-64 reduce
    for (int off = 32; off > 0; off >>= 1)
        s += __shfl_down(s, off, 64);

    __shared__ float wsum[3];
    if ((t & 63) == 0) wsum[t >> 6] = s;
    __syncthreads();
    if (t == 0) {
        float tot  = wsum[0] + wsum[1] + wsum[2];
        float sign = is_ans[bn] ? -1.f : 1.f;
        atomicAdd(&slots[blockIdx.x & (NSLOTS - 1)], tot * sign);
    }
}

// ---------------------------------------------------------------------------
// Kernel 3: reduce the 64 slots, apply 1/(Lq*Ld)
// ---------------------------------------------------------------------------
__global__ void finish_kernel(const float* __restrict__ slots, float* __restrict__ out) {
    float s = slots[threadIdx.x];
    for (int off = 32; off > 0; off >>= 1)
        s += __shfl_down(s, off, 64);
    if (threadIdx.x == 0)
        out[0] = s * (1.f / ((float)LQ * (float)LD));
}

extern "C" void kernel_launch(void* const* d_in, const int* in_sizes, int n_in,
                              void* d_out, int out_size, void* d_ws, size_t ws_size,
                              hipStream_t stream) {
    const float* q      = (const float*)d_in[0];   // [B, Lq, D] f32
    const float* docs   = (const float*)d_in[1];   // [B, N, Ld, D] f32
    const int*   is_ans = (const int*)d_in[2];     // [B, N] bool -> int32
    float* out  = (float*)d_out;

    float* qsum  = (float*)d_ws;                   // [B*D]
    float* slots = qsum + QSUM_ELEMS;              // [NSLOTS]

    // zero the accumulators (ws is poisoned 0xAA before every call)
    hipMemsetAsync(d_ws, 0, (QSUM_ELEMS + NSLOTS) * sizeof(float), stream);

    qsum_kernel<<<dim3(QSUM_ELEMS / 256, LQ_CHUNKS), 256, 0, stream>>>(q, qsum);
    docs_kernel<<<dim3(BB * NN * CH), 192, 0, stream>>>(docs, is_ans, qsum, slots);
    finish_kernel<<<1, 64, 0, stream>>>(slots, out);
}

// Round 2
// 531.233 us; speedup vs baseline: 1.0100x; 1.0100x over previous
//
#include <hip/hip_runtime.h>

// Problem constants (from setup_inputs): B=32, N=8, Lq=256, Ld=512, D=768
#define BB 32
#define NN 8
#define LQ 256
#define LD 512
#define DD 768

#define QCH 8                         // lq chunks in qsum kernel
#define QROWS (LQ / QCH)              // 32 rows per chunk
#define QPART_ELEMS (QCH * BB * DD)   // 196608 floats (~786 KB) in ws
#define CH 8                          // l-chunks per (b,n) doc in docs kernel
#define LCHUNK (LD / CH)              // 64 rows per block
#define NBLK (BB * NN * CH)           // 2048 docs blocks

// ---------------------------------------------------------------------------
// Kernel 1: qpart[c][b][d] = sum of 32 lq rows. Direct write, no atomics,
// no memset needed. grid (96, 8) x 256 threads; 8 independent acc chains.
// ---------------------------------------------------------------------------
__global__ void __launch_bounds__(256)
qsum_kernel(const float* __restrict__ q, float* __restrict__ qpart) {
    int bd = blockIdx.x;                 // 0..95 -> (b, d-chunk of 256)
    int b  = bd / 3;
    int dc = bd - b * 3;
    int d  = dc * 256 + threadIdx.x;
    int c  = blockIdx.y;                 // lq chunk
    const float* p = q + ((size_t)b * LQ + (size_t)c * QROWS) * DD + d;
    float a0 = 0.f, a1 = 0.f, a2 = 0.f, a3 = 0.f;
    float a4 = 0.f, a5 = 0.f, a6 = 0.f, a7 = 0.f;
#pragma unroll
    for (int i = 0; i < QROWS; i += 8) {
        a0 += p[(size_t)(i + 0) * DD];
        a1 += p[(size_t)(i + 1) * DD];
        a2 += p[(size_t)(i + 2) * DD];
        a3 += p[(size_t)(i + 3) * DD];
        a4 += p[(size_t)(i + 4) * DD];
        a5 += p[(size_t)(i + 5) * DD];
        a6 += p[(size_t)(i + 6) * DD];
        a7 += p[(size_t)(i + 7) * DD];
    }
    qpart[((size_t)c * BB + b) * DD + d] = ((a0 + a1) + (a2 + a3)) + ((a4 + a5) + (a6 + a7));
}

// ---------------------------------------------------------------------------
// Kernel 2: stream docs once. Block = (b,n, l-chunk), 192 threads = 3 waves.
// Thread t owns float4 column d=4t; sums its qpart fragments (L2-resident)
// in the prologue, then 64 rows of coalesced float4 loads. One store/block.
// ---------------------------------------------------------------------------
__global__ void __launch_bounds__(192)
docs_kernel(const float* __restrict__ docs, const int* __restrict__ is_ans,
            const float* __restrict__ qpart, float* __restrict__ partials) {
    int bn    = blockIdx.x / CH;          // 0 .. 255
    int chunk = blockIdx.x - bn * CH;     // 0 .. 7
    int b     = bn >> 3;                  // bn / N
    int t     = threadIdx.x;              // 0 .. 191

    float4 qv = make_float4(0.f, 0.f, 0.f, 0.f);
#pragma unroll
    for (int c = 0; c < QCH; ++c) {
        float4 v = *(const float4*)(qpart + ((size_t)c * BB + b) * DD + 4 * t);
        qv.x += v.x; qv.y += v.y; qv.z += v.z; qv.w += v.w;
    }

    const float4* p = (const float4*)(docs + ((size_t)bn * LD + (size_t)chunk * LCHUNK) * DD) + t;

    float4 acc = make_float4(0.f, 0.f, 0.f, 0.f);
#pragma unroll 8
    for (int l = 0; l < LCHUNK; ++l) {
        float4 v = p[(size_t)l * (DD / 4)];   // 16B/lane, 192 lanes cover one row
        acc.x += v.x * qv.x;
        acc.y += v.y * qv.y;
        acc.z += v.z * qv.z;
        acc.w += v.w * qv.w;
    }
    float s = acc.x + acc.y + acc.z + acc.w;

    // wave-64 reduce
    for (int off = 32; off > 0; off >>= 1)
        s += __shfl_down(s, off, 64);

    __shared__ float wsum[3];
    if ((t & 63) == 0) wsum[t >> 6] = s;
    __syncthreads();
    if (t == 0) {
        float sign = is_ans[bn] ? -1.f : 1.f;
        partials[blockIdx.x] = (wsum[0] + wsum[1] + wsum[2]) * sign;
    }
}

// ---------------------------------------------------------------------------
// Kernel 3: reduce 2048 per-block partials, apply 1/(Lq*Ld)
// ---------------------------------------------------------------------------
__global__ void __launch_bounds__(256)
finish_kernel(const float* __restrict__ partials, float* __restrict__ out) {
    int t = threadIdx.x;
    float s = 0.f;
#pragma unroll
    for (int i = 0; i < NBLK; i += 256)
        s += partials[i + t];
    for (int off = 32; off > 0; off >>= 1)
        s += __shfl_down(s, off, 64);
    __shared__ float wsum[4];
    if ((t & 63) == 0) wsum[t >> 6] = s;
    __syncthreads();
    if (t == 0)
        out[0] = (wsum[0] + wsum[1] + wsum[2] + wsum[3]) * (1.f / ((float)LQ * (float)LD));
}

extern "C" void kernel_launch(void* const* d_in, const int* in_sizes, int n_in,
                              void* d_out, int out_size, void* d_ws, size_t ws_size,
                              hipStream_t stream) {
    const float* q      = (const float*)d_in[0];   // [B, Lq, D] f32
    const float* docs   = (const float*)d_in[1];   // [B, N, Ld, D] f32
    const int*   is_ans = (const int*)d_in[2];     // [B, N] bool -> int
    float* out = (float*)d_out;

    float* qpart    = (float*)d_ws;                // [QCH*B*D]
    float* partials = qpart + QPART_ELEMS;         // [NBLK]

    qsum_kernel<<<dim3(BB * 3, QCH), 256, 0, stream>>>(q, qpart);
    docs_kernel<<<dim3(NBLK), 192, 0, stream>>>(docs, is_ans, qpart, partials);
    finish_kernel<<<1, 256, 0, stream>>>(partials, out);
}